// Round 8
// baseline (117.535 us; speedup 1.0000x reference)
//
#include <hip/hip_runtime.h>
#include <stdint.h>

#define BB 8
#define C  64
#define H  256
#define W  256
#define HW (H*W)
#define EPSV 1e-6f

typedef unsigned long long u64;
typedef float __attribute__((ext_vector_type(4))) f32x4;

// ------- K1: fused sign-pack + stats (LDS transpose, XOR-swizzled) -------
// 1024 blocks (b = blk>>7, 2-row strip rg), 256 threads, 4 tiles of 64ch x 128px.
// Load phase: coalesced f32x4, swizzled LDS write (permutation within row).
// Consume phase: lane=channel; register stats accumulation + ballot pack.
__global__ __launch_bounds__(256) void k_packstats(
    const float* __restrict__ x,
    const float* __restrict__ bmove,
    u64* __restrict__ packed,
    float* __restrict__ part /* [512 bc][3 st][128 rg] */) {
  int blk = blockIdx.x;
  int b   = blk >> 7;
  int rg  = blk & 127;
  int h0  = rg << 1;
  int tid = threadIdx.x;
  int wid = tid >> 6, lane = tid & 63;

  __shared__ f32x4 lds4[64 * 32];     // [c][32 chunks], chunk idx XOR-swizzled
  __shared__ float sred[4][3][64];

  float bm = bmove[lane];             // lane = channel in consume phase
  float s = 0.f, s2 = 0.f, sa = 0.f;

  int p4l = tid & 31;                 // load phase: f4 chunk within 128px
  int cg  = tid >> 5;                 // load phase: channel sub-group 0..7
  const size_t bbase = (size_t)b * C * HW;

  for (int tile = 0; tile < 4; ++tile) {
    int h  = h0 + (tile >> 1);
    int wb = (tile & 1) << 7;
    __syncthreads();
    #pragma unroll
    for (int cc = 0; cc < 8; ++cc) {
      int c = cg + (cc << 3);
      lds4[(c << 5) + (p4l ^ (c & 7))] =
          *((const f32x4*)(x + bbase + (size_t)c * HW + h * W + wb) + p4l);
    }
    __syncthreads();
    u64* pdst = packed + ((size_t)(b * H + h)) * W + wb;
    #pragma unroll
    for (int k = 0; k < 8; ++k) {
      int p4i = (wid << 3) + k;
      f32x4 v = lds4[(lane << 5) + (p4i ^ (lane & 7))];
      float a0 = v.x + bm, a1 = v.y + bm, a2 = v.z + bm, a3 = v.w + bm;
      s  += (a0 + a1) + (a2 + a3);
      s2 += a0*a0 + a1*a1 + a2*a2 + a3*a3;
      sa += (fabsf(a0) + fabsf(a1)) + (fabsf(a2) + fabsf(a3));
      u64 q0 = __ballot(a0 > 0.f);
      u64 q1 = __ballot(a1 > 0.f);
      u64 q2 = __ballot(a2 > 0.f);
      u64 q3 = __ballot(a3 > 0.f);
      u64 qa = (lane & 1) ? q1 : q0;
      u64 qb = (lane & 1) ? q3 : q2;
      u64 qq = (lane & 2) ? qb : qa;
      if (lane < 4) pdst[(p4i << 2) + lane] = qq;
    }
  }
  sred[wid][0][lane] = s;
  sred[wid][1][lane] = s2;
  sred[wid][2][lane] = sa;
  __syncthreads();
  if (tid < 192) {
    int st = tid >> 6, c = tid & 63;
    float v = sred[0][st][c] + sred[1][st][c] + sred[2][st][c] + sred[3][st][c];
    part[((size_t)(b * 64 + c) * 3 + st) * 128 + rg] = v;
  }
}

// ---------------- K2: finish stats, gate (conv1d over C + sigmoid), weights --
__global__ __launch_bounds__(512) void k_gate(
    const float* __restrict__ part,
    const float* __restrict__ w_conv,
    const float* __restrict__ w1d,
    float* __restrict__ alpha,
    u64* __restrict__ wsign) {
  __shared__ float stA[512], stM[512], stS[512];  // [b*64 + c]
  __shared__ float swv[64];
  int tid = threadIdx.x;
  {
    const f32x4* p = (const f32x4*)(part + (size_t)tid * 384);
    float s = 0.f, s2 = 0.f, sa = 0.f;
    for (int k = 0;  k < 32; k++) { f32x4 v = p[k]; s  += (v.x + v.y) + (v.z + v.w); }
    for (int k = 32; k < 64; k++) { f32x4 v = p[k]; s2 += (v.x + v.y) + (v.z + v.w); }
    for (int k = 64; k < 96; k++) { f32x4 v = p[k]; sa += (v.x + v.y) + (v.z + v.w); }
    const float invN = 1.f / (float)HW;
    float mean = s * invN;
    float var  = (s2 - s * s * invN) * (1.f / (float)(HW - 1)) + EPSV;
    stA[tid] = sa * invN;
    stM[tid] = mean;
    stS[tid] = sqrtf(var);
  }
  {
    int o = tid >> 3, g = tid & 7;                 // 8 lanes per out-channel
    const float* wo = w_conv + o * 576 + g * 72;   // 8 in-channels x 9 taps
    float s = 0.f;
    u64 wb[9] = {0,0,0,0,0,0,0,0,0};
    #pragma unroll
    for (int i = 0; i < 8; i++) {
      #pragma unroll
      for (int tp = 0; tp < 9; tp++) {
        float v = wo[i * 9 + tp];
        s += fabsf(v);
        if (v > 0.f) wb[tp] |= (1ull << (g * 8 + i));
      }
    }
    #pragma unroll
    for (int off = 4; off > 0; off >>= 1) {
      s += __shfl_down(s, off, 8);
      #pragma unroll
      for (int tp = 0; tp < 9; tp++)
        wb[tp] |= __shfl_down(wb[tp], off, 8);
    }
    if (g == 0) {
      swv[o] = s * (1.f / 576.f);
      #pragma unroll
      for (int tp = 0; tp < 9; tp++) wsign[o * 9 + tp] = wb[tp];
    }
  }
  __syncthreads();
  int b = tid >> 6, c = tid & 63;
  float y = 0.f;
  #pragma unroll
  for (int k = 0; k < 3; k++) {
    int cc = c + k - 1;
    if (cc >= 0 && cc < 64) {
      int j = b * 64 + cc;
      y += stA[j] * w1d[0 * 3 + k] + stM[j] * w1d[1 * 3 + k] + stS[j] * w1d[2 * 3 + k];
    }
  }
  float gate = 1.f / (1.f + expf(-y));
  alpha[tid] = gate * swv[c];   // folds scale_w[o] * gate[b][o]
}

// ---------------- K3: XNOR conv, 4 px/thread, o-split x4 (unchanged R6) -----
// 2048 blocks: blk = b*256 + hg*4 + oq. Block: 4-row strip, o in [oq*16, +16).
__global__ __launch_bounds__(256) void k_conv4(const u64* __restrict__ packed,
                                               const u64* __restrict__ wsign,
                                               const float* __restrict__ alpha,
                                               const float* __restrict__ x,
                                               const float* __restrict__ pr_b0,
                                               const float* __restrict__ prelu_a,
                                               const float* __restrict__ pr_b1,
                                               float* __restrict__ out) {
  int blk = blockIdx.x;
  int oq = blk & 3;
  int hg = (blk >> 2) & 63;
  int b  = blk >> 8;
  int h0 = hg << 2;
  int t = threadIdx.x;
  __shared__ u64 rows[6][W];          // packed rows h0-1 .. h0+4
  const u64* pb = packed + (size_t)b * H * W;
  #pragma unroll
  for (int r = 0; r < 6; ++r) {
    int hr = h0 - 1 + r;
    rows[r][t] = (hr >= 0 && hr < H) ? pb[hr * W + t] : 0ull;
  }
  __syncthreads();

  int tr = t >> 6, lane = t & 63;
  int tw = lane << 2;
  int h  = h0 + tr;
  bool rTop = (h > 0), rBot = (h < H - 1);       // wave-uniform
  u64 vm0 = (lane == 0)  ? 0ull : ~0ull;
  u64 vm5 = (lane == 63) ? 0ull : ~0ull;

  u64 nw[3][6];
  #pragma unroll
  for (int rr = 0; rr < 3; ++rr) {
    #pragma unroll
    for (int j = 0; j < 6; ++j) {
      int wi = tw - 1 + j;
      wi = (wi < 0) ? 0 : (wi > W - 1 ? W - 1 : wi);
      nw[rr][j] = rows[tr + rr][wi];
    }
  }
  int nr = 1 + (int)rTop + (int)rBot;
  float base0 = 64.f * (float)nr * ((lane == 0)  ? 2.f : 3.f);
  float base1 = 64.f * (float)nr * 3.f;
  float base3 = 64.f * (float)nr * ((lane == 63) ? 2.f : 3.f);

  int o0 = oq << 4;
  size_t xoff = (size_t)b * C * HW + (size_t)(o0) * HW + (size_t)h * W + tw;
  const float* al = alpha + b * 64 + o0;
  const float* pb0 = pr_b0 + o0;
  const float* ppa = prelu_a + o0;
  const float* pb1 = pr_b1 + o0;
  const u64* wsq = wsign + (size_t)o0 * 9;

  #pragma unroll 2
  for (int oo = 0; oo < 16; ++oo) {
    const u64* ws = wsq + oo * 9;
    u64 w0=ws[0], w1=ws[1], w2=ws[2], w3=ws[3], w4=ws[4],
        w5=ws[5], w6=ws[6], w7=ws[7], w8=ws[8];
    f32x4 xr = *(const f32x4*)(x + xoff + (size_t)oo * HW);
    int c0 = 0, c1 = 0, c2 = 0, c3 = 0;
    if (rTop) {
      c0 += __popcll((nw[0][0]^w0)&vm0) + __popcll(nw[0][1]^w1) + __popcll(nw[0][2]^w2);
      c1 += __popcll(nw[0][1]^w0) + __popcll(nw[0][2]^w1) + __popcll(nw[0][3]^w2);
      c2 += __popcll(nw[0][2]^w0) + __popcll(nw[0][3]^w1) + __popcll(nw[0][4]^w2);
      c3 += __popcll(nw[0][3]^w0) + __popcll(nw[0][4]^w1) + __popcll((nw[0][5]^w2)&vm5);
    }
    {
      c0 += __popcll((nw[1][0]^w3)&vm0) + __popcll(nw[1][1]^w4) + __popcll(nw[1][2]^w5);
      c1 += __popcll(nw[1][1]^w3) + __popcll(nw[1][2]^w4) + __popcll(nw[1][3]^w5);
      c2 += __popcll(nw[1][2]^w3) + __popcll(nw[1][3]^w4) + __popcll(nw[1][4]^w5);
      c3 += __popcll(nw[1][3]^w3) + __popcll(nw[1][4]^w4) + __popcll((nw[1][5]^w5)&vm5);
    }
    if (rBot) {
      c0 += __popcll((nw[2][0]^w6)&vm0) + __popcll(nw[2][1]^w7) + __popcll(nw[2][2]^w8);
      c1 += __popcll(nw[2][1]^w6) + __popcll(nw[2][2]^w7) + __popcll(nw[2][3]^w8);
      c2 += __popcll(nw[2][2]^w6) + __popcll(nw[2][3]^w7) + __popcll(nw[2][4]^w8);
      c3 += __popcll(nw[2][3]^w6) + __popcll(nw[2][4]^w7) + __popcll((nw[2][5]^w8)&vm5);
    }
    float a  = al[oo];
    float b0 = pb0[oo], pa = ppa[oo], b1 = pb1[oo];
    float d0 = (base0 - 2.f*(float)c0) * a + b0;
    float d1 = (base1 - 2.f*(float)c1) * a + b0;
    float d2 = (base1 - 2.f*(float)c2) * a + b0;
    float d3 = (base3 - 2.f*(float)c3) * a + b0;
    d0 = (d0 > 0.f) ? d0 : pa * d0;
    d1 = (d1 > 0.f) ? d1 : pa * d1;
    d2 = (d2 > 0.f) ? d2 : pa * d2;
    d3 = (d3 > 0.f) ? d3 : pa * d3;
    f32x4 ov;
    ov.x = d0 + b1 + xr.x;
    ov.y = d1 + b1 + xr.y;
    ov.z = d2 + b1 + xr.z;
    ov.w = d3 + b1 + xr.w;
    __builtin_nontemporal_store(ov, (f32x4*)(out + xoff + (size_t)oo * HW));
  }
}

extern "C" void kernel_launch(void* const* d_in, const int* in_sizes, int n_in,
                              void* d_out, int out_size, void* d_ws, size_t ws_size,
                              hipStream_t stream) {
  const float* x       = (const float*)d_in[0];
  const float* b_move  = (const float*)d_in[1];
  const float* w_conv  = (const float*)d_in[2];
  const float* w1d     = (const float*)d_in[3];
  const float* pr_b0   = (const float*)d_in[4];
  const float* prelu_a = (const float*)d_in[5];
  const float* pr_b1   = (const float*)d_in[6];
  float* out = (float*)d_out;

  char* ws = (char*)d_ws;
  // ws: packed u64[8*256*256] = 4 MiB; part = 512*3*128 f32 (768 KiB);
  // alpha 512 f32; wsign 576 u64
  u64*   packed = (u64*)ws;
  float* part   = (float*)(ws + 4194304);
  float* alpha  = (float*)(ws + 4194304 + 786432);
  u64*   wsign  = (u64*)(ws + 4194304 + 786432 + 4096);

  k_packstats<<<1024, 256, 0, stream>>>(x, b_move, packed, part);
  k_gate<<<1, 512, 0, stream>>>(part, w_conv, w1d, alpha, wsign);
  k_conv4<<<2048, 256, 0, stream>>>(packed, wsign, alpha, x,
                                    pr_b0, prelu_a, pr_b1, out);
}